// Round 5
// baseline (1713.941 us; speedup 1.0000x reference)
//
#include <hip/hip_runtime.h>

// DCT upsample: out[img] = M * x[img] * M^T,  M = E*D (960x768), closed-form
// Dirichlet kernel:
//   M[i][n] = (1 + S(p1) + S(p2))/960,  S = sin(767u)cos(768u)/sin(u), u=pi*p/15360
// Restructured so M is the A operand of BOTH gemms:
//   T' = M * x^T      (Bt = xb bf16, separate conv pass)   [960 x 768]
//   out = M * T'^T    (Bt = T')                            [960 x 960]
// V6 = V3 schedule + occupancy doubling:
//   256x256 tile, BK=32 (was 64) -> LDS 64 KiB -> 2 blocks/CU (16 waves/CU).
//   One block's barrier/vmcnt stalls overlap the other block's MFMA bursts
//   (m114 co-scheduling). Barrier count and per-barrier MFMA unchanged
//   (4 barriers x 24 tiles == 8 x 12), LDS traffic unchanged.
//   2 phases per K-tile (C top-half / bottom-half):
//     P1: [read afr0-3,bfr0-3 | stage A(t+1)] bar; lgkm0+schedbar; prio1;
//         16 MFMA; prio0; bar
//     P2: [read afr4-7        | stage B(t+1)] bar; lgkm0+schedbar; prio1;
//         16 MFMA; prio0; vm0; bar   (vm0: publish buffer n)
//   XOR chunk swizzle (4 chunks/row): phys 16B-chunk p of row r holds
//   logical p^((r>>1)&3), applied on the per-lane global source (LDS dest
//   linear, glds16); fragment reads apply the same XOR.

#define HW 768
#define OHW 960
#define NIMG 48

typedef __attribute__((ext_vector_type(8))) short short8;
typedef __attribute__((ext_vector_type(4))) float f32x4;
typedef __attribute__((ext_vector_type(4))) float float4v;
typedef __attribute__((ext_vector_type(4))) unsigned short us4;

__device__ __forceinline__ unsigned short f2bf(float f) {
    union { float f; unsigned int u; } v; v.f = f;
    unsigned int u = v.u;
    return (unsigned short)((u + 0x7FFFu + ((u >> 16) & 1u)) >> 16);
}

__device__ __forceinline__ void glds16(const void* g, void* l) {
    __builtin_amdgcn_global_load_lds(
        (const __attribute__((address_space(1))) void*)g,
        (__attribute__((address_space(3))) void*)l, 16, 0, 0);
}

// ---------------- closed-form M fill ----------------
__device__ __forceinline__ float dsum(int p) {
    int n1 = (767 * p) % 30720;
    int n2 = (768 * p) % 30720;
    const float w = (float)(3.14159265358979323846 / 15360.0);
    return sinf((float)n1 * w) * cosf((float)n2 * w) / sinf((float)p * w);
}

__global__ void fill_M(unsigned short* __restrict__ Mb) {
    int idx = blockIdx.x * 256 + threadIdx.x;
    if (idx >= OHW * HW) return;
    int i = idx / HW, n = idx - i * HW;
    int a = 8 * i + 4, b = 10 * n + 5;
    int p1 = a + b;
    int p2 = a - b; if (p2 < 0) p2 += 15360;
    float m = (1.0f + dsum(p1) + dsum(p2)) * (1.0f / 960.0f);
    Mb[idx] = f2bf(m);
}

// ---------------- streaming f32 -> bf16 convert ----------------
__global__ void conv_bf16(const float* __restrict__ x, unsigned short* __restrict__ xb, int n4) {
    int i = blockIdx.x * 256 + threadIdx.x;
    if (i >= n4) return;
    float4v v = *(const float4v*)(x + (size_t)i * 4);
    us4 o; o.x = f2bf(v.x); o.y = f2bf(v.y); o.z = f2bf(v.z); o.w = f2bf(v.w);
    *(us4*)(xb + (size_t)i * 4) = o;
}

// ---------------- MFMA GEMM (B-transposed, K-major operands) ----------------
#define ASM_BAR   asm volatile("s_barrier" ::: "memory")
#define ASM_VM0   asm volatile("s_waitcnt vmcnt(0)" ::: "memory")
#define ASM_LGKM0 do { asm volatile("s_waitcnt lgkmcnt(0)" ::: "memory"); \
                       __builtin_amdgcn_sched_barrier(0); } while (0)

__global__ __launch_bounds__(512, 4) void gemm_bt(
    const unsigned short* __restrict__ A, int lda,
    const unsigned short* __restrict__ Bg, long long strideB, int ldb,
    void* __restrict__ Cg, long long strideC, int ldc,
    int Md, int Nd, int Kd, int out_f32)
{
    __shared__ unsigned short As[2][256 * 32];
    __shared__ unsigned short Bs[2][256 * 32];

    const int tid = threadIdx.x;
    const int wave = tid >> 6, lane = tid & 63;
    const int wm = wave >> 2, wn = wave & 3;     // 2 x 4 wave grid
    const int t16 = lane & 15, quad = lane >> 4;
    const int z = blockIdx.z;

    const unsigned short* Bp = Bg + (size_t)z * strideB;
    const int mb = blockIdx.y * 256, nbb = blockIdx.x * 256;

    f32x4 acc[8][4];
#pragma unroll
    for (int i = 0; i < 8; ++i)
#pragma unroll
        for (int j = 0; j < 4; ++j)
            acc[i][j] = (f32x4){0.f, 0.f, 0.f, 0.f};

    // ---- staging geometry (pre-swizzled per-lane global source) ----
    // 16B-chunk c = tid + 512*j (j=0,1) -> row r = c>>2 (0..255),
    // phys p = c&3 = tid&3, logical l = p ^ ((r>>1)&3) = (tid&3)^((tid>>3)&3)
    const int srow = tid >> 2;                             // 0..127
    const int klog = ((tid & 3) ^ ((tid >> 3) & 3)) * 8;   // shorts
    const unsigned short* pA[2];
    const unsigned short* pB[2];
#pragma unroll
    for (int j = 0; j < 2; ++j) {
        int ra = mb + srow + 128 * j;  if (ra >= Md) ra = Md - 1;
        int rb = nbb + srow + 128 * j; if (rb >= Nd) rb = Nd - 1;
        pA[j] = A + (size_t)ra * lda + klog;
        pB[j] = Bp + (size_t)rb * ldb + klog;
    }
    const int dOff = tid * 8;   // LDS shorts; + j*4096 per chunk

    // ---- fragment read offsets (shorts) ----
    // row = base16*16 + t16 (base16*16 % 16 == 0) -> (row>>1)&3 = (t16>>1)&3
    const int swz = (t16 >> 1) & 3;
    const int ph = (quad ^ swz) * 8;
    const int aRow = (wm * 128 + t16) * 32;
    const int bRow = (wn * 64 + t16) * 32;

#define RD_A(lo) do { _Pragma("unroll")                                       \
    for (int mi_ = 0; mi_ < 4; ++mi_)                                         \
        afr[(lo) + mi_] = *(const short8*)(Asc + aRow + ((lo)+mi_)*512 + ph); \
    } while (0)

#define RD_B() do { _Pragma("unroll")                                        \
    for (int ni_ = 0; ni_ < 4; ++ni_)                                        \
        bfr[ni_] = *(const short8*)(Bsc + bRow + ni_ * 512 + ph);            \
    } while (0)

#define MMA_H(h) do {                                                         \
    __builtin_amdgcn_s_setprio(1);                                            \
    _Pragma("unroll")                                                         \
    for (int mi_ = 0; mi_ < 4; ++mi_)                                         \
    _Pragma("unroll")                                                         \
    for (int ni_ = 0; ni_ < 4; ++ni_)                                         \
        acc[(h)*4+mi_][ni_] = __builtin_amdgcn_mfma_f32_16x16x32_bf16(        \
            afr[(h)*4+mi_], bfr[ni_], acc[(h)*4+mi_][ni_], 0, 0, 0);          \
    __builtin_amdgcn_s_setprio(0); } while (0)

#define STG_A(buf, stk) do { _Pragma("unroll")                                \
    for (int j_ = 0; j_ < 2; ++j_)                                            \
        glds16(pA[j_] + (stk), &As[buf][0] + dOff + j_ * 4096); } while (0)
#define STG_B(buf, stk) do { _Pragma("unroll")                                \
    for (int j_ = 0; j_ < 2; ++j_)                                            \
        glds16(pB[j_] + (stk), &Bs[buf][0] + dOff + j_ * 4096); } while (0)

    const int NT = Kd >> 5;   // K=768 -> 24 tiles

    // prologue: stage tile 0 into buf 0
    STG_A(0, 0); STG_B(0, 0);
    ASM_VM0;
    ASM_BAR;

    for (int t = 0; t < NT; ++t) {
        const int c = t & 1, n = c ^ 1;
        const unsigned short* Asc = &As[c][0];
        const unsigned short* Bsc = &Bs[c][0];
        const bool pf = (t + 1 < NT);
        const int stk = (t + 1) * 32;
        short8 afr[8], bfr[4];

        // ---- P1: top half (8 reads; stage A of t+1) ----
        RD_A(0); RD_B();
        if (pf) STG_A(n, stk);
        ASM_BAR;
        ASM_LGKM0;
        MMA_H(0);
        ASM_BAR;

        // ---- P2: bottom half (4 reads; stage B of t+1) ----
        RD_A(4);
        if (pf) STG_B(n, stk);
        ASM_BAR;
        ASM_LGKM0;
        MMA_H(1);
        ASM_VM0;     // staging for t+1 issued this tile -> publish buffer n
        ASM_BAR;
    }

#undef RD_A
#undef RD_B
#undef MMA_H
#undef STG_A
#undef STG_B

    // epilogue: D row = quad*4 + r, col = t16 within each 16x16 tile
    const int gr0 = mb + wm * 128;
    const int gc0 = nbb + wn * 64;
    if (out_f32) {
        float* C = (float*)Cg + (size_t)z * strideC;
#pragma unroll
        for (int mi = 0; mi < 8; ++mi)
#pragma unroll
            for (int ni = 0; ni < 4; ++ni) {
                int col = gc0 + ni * 16 + t16;
                if (col < Nd) {
#pragma unroll
                    for (int r = 0; r < 4; ++r) {
                        int rowg = gr0 + mi * 16 + quad * 4 + r;
                        if (rowg < Md) C[(size_t)rowg * ldc + col] = acc[mi][ni][r];
                    }
                }
            }
    } else {
        unsigned short* C = (unsigned short*)Cg + (size_t)z * strideC;
#pragma unroll
        for (int mi = 0; mi < 8; ++mi)
#pragma unroll
            for (int ni = 0; ni < 4; ++ni) {
                int col = gc0 + ni * 16 + t16;
                if (col < Nd) {
#pragma unroll
                    for (int r = 0; r < 4; ++r) {
                        int rowg = gr0 + mi * 16 + quad * 4 + r;
                        if (rowg < Md) C[(size_t)rowg * ldc + col] = f2bf(acc[mi][ni][r]);
                    }
                }
            }
    }
}

extern "C" void kernel_launch(void* const* d_in, const int* in_sizes, int n_in,
                              void* d_out, int out_size, void* d_ws, size_t ws_size,
                              hipStream_t stream) {
    const float* x = (const float*)d_in[0];
    float* out = (float*)d_out;
    char* ws = (char*)d_ws;

    size_t offM  = 0;
    size_t fixed = offM + (size_t)OHW * HW * 2;              // 1,474,560 B
    size_t perImg = (size_t)HW * HW * 2 + (size_t)OHW * HW * 2;

    int nb = 1;
    if (ws_size > fixed + perImg) {
        size_t q = (ws_size - fixed) / perImg;
        nb = (q > 48) ? 48 : (int)q;
        if (nb < 1) nb = 1;
    }

    unsigned short* Mb = (unsigned short*)(ws + offM);
    unsigned short* xb = (unsigned short*)(ws + fixed);
    unsigned short* T  = (unsigned short*)(ws + fixed + (size_t)nb * HW * HW * 2);

    fill_M<<<(OHW * HW + 255) / 256, 256, 0, stream>>>(Mb);

    for (int b0 = 0; b0 < NIMG; b0 += nb) {
        int cur = NIMG - b0; if (cur > nb) cur = nb;
        // xb = bf16(x[b0..b0+cur]), streaming convert
        int n4 = cur * (HW * HW / 4);
        conv_bf16<<<(n4 + 255) / 256, 256, 0, stream>>>(
            x + (size_t)b0 * HW * HW, xb, n4);
        // T' = M * x^T   (A = M [960x768], Bt = xb [768 rows x 768 K])
        gemm_bt<<<dim3(3, 4, cur), 512, 0, stream>>>(
            Mb, HW, xb, (long long)HW * HW, HW,
            T, (long long)OHW * HW, HW, OHW, HW, HW, 0);
        // out = M * T'^T (A = M, Bt = T' [960 rows x 768 K])
        gemm_bt<<<dim3(4, 4, cur), 512, 0, stream>>>(
            Mb, HW, T, (long long)OHW * HW, HW,
            out + (size_t)b0 * OHW * OHW, (long long)OHW * OHW, OHW,
            OHW, OHW, HW, 1);
    }
    (void)in_sizes; (void)n_in; (void)out_size;
}